// Round 1
// baseline (430.443 us; speedup 1.0000x reference)
//
#include <hip/hip_runtime.h>

// DeletionChannel: B=4096, L=128, V=64, P=0.1
// out[0 : B*L*V)          = compacted messages with EOS tail
// out[B*L*V : 2*B*L*V)    = rescaled probs
constexpr int Bn = 4096;
constexpr int Ln = 128;
constexpr int Vn = 64;
constexpr float KEEP = 0.9f;  // 1 - P

__global__ __launch_bounds__(256) void deletion_channel_kernel(
    const float* __restrict__ msgs,
    const float* __restrict__ probs,
    const int* __restrict__ mask,
    float* __restrict__ out)
{
    const int b   = blockIdx.x;
    const int tid = threadIdx.x;
    const int lane = tid & 63;
    const int wave = tid >> 6;

    __shared__ int s_src[Ln];     // s_src[j] = source row of j-th kept symbol
    __shared__ int s_wavecnt[2];

    // ---- Phase 1: compaction map from deletion mask (waves 0-1 only) ----
    bool kept = false;
    int rank = 0;
    if (tid < Ln) kept = (mask[(size_t)b * Ln + tid] == 0);
    if (wave < 2) {  // waves 0 and 1 fully cover tid 0..127
        unsigned long long bal = __ballot(kept);
        rank = __popcll(bal & ((1ull << lane) - 1ull));
        if (lane == 0) s_wavecnt[wave] = (int)__popcll(bal);
    }
    __syncthreads();
    if (tid < Ln && kept) {
        const int off = (wave == 1) ? s_wavecnt[0] : 0;
        s_src[off + rank] = tid;
    }
    __syncthreads();
    const int nkept = s_wavecnt[0] + s_wavecnt[1];

    const size_t rowbase = (size_t)b * (Ln * Vn);  // in floats

    // ---- Phase 2: gather-copy messages (float4, coalesced) ----
    {
        const float4* __restrict__ src4 = (const float4*)(msgs + rowbase);
        float4* __restrict__ dst4       = (float4*)(out + rowbase);
        constexpr int TOT4 = Ln * Vn / 4;  // 2048 float4 per batch row
        #pragma unroll
        for (int it = 0; it < TOT4 / 256; ++it) {
            const int idx = it * 256 + tid;
            const int j = idx >> 4;    // output sequence position
            const int q = idx & 15;    // float4 within the 64-float row
            float4 v;
            if (j < nkept) {
                v = src4[(s_src[j] << 4) + q];
            } else {
                v = make_float4((q == 0) ? 1.0f : 0.0f, 0.0f, 0.0f, 0.0f);  // EOS one-hot
            }
            dst4[idx] = v;
        }
    }

    // ---- Phase 3: probs rescale (float4 + 16-lane shfl reduction) ----
    {
        const float4* __restrict__ src4 = (const float4*)(probs + rowbase);
        float4* __restrict__ dst4 = (float4*)(out + (size_t)Bn * Ln * Vn + rowbase);
        constexpr int TOT4 = Ln * Vn / 4;
        #pragma unroll
        for (int it = 0; it < TOT4 / 256; ++it) {
            const int idx = it * 256 + tid;
            const int q = idx & 15;
            const float4 p = src4[idx];
            // tail sum (v >= 1) of this row, reduced across the 16 lanes of the row
            float s = p.x + p.y + p.z + p.w;
            if (q == 0) s -= p.x;           // exclude v=0
            s += __shfl_xor(s, 1);
            s += __shfl_xor(s, 2);
            s += __shfl_xor(s, 4);
            s += __shfl_xor(s, 8);
            float4 o = make_float4(p.x * KEEP, p.y * KEEP, p.z * KEEP, p.w * KEEP);
            if (q == 0) o.x = 1.0f - KEEP * s;  // EOS absorbs remainder
            dst4[idx] = o;
        }
    }
}

extern "C" void kernel_launch(void* const* d_in, const int* in_sizes, int n_in,
                              void* d_out, int out_size, void* d_ws, size_t ws_size,
                              hipStream_t stream) {
    const float* msgs  = (const float*)d_in[0];
    const float* probs = (const float*)d_in[1];
    const int*   mask  = (const int*)d_in[2];
    float* out = (float*)d_out;

    deletion_channel_kernel<<<Bn, 256, 0, stream>>>(msgs, probs, mask, out);
}

// Round 7
// 420.893 us; speedup vs baseline: 1.0227x; 1.0227x over previous
//
#include <hip/hip_runtime.h>

// DeletionChannel: B=4096, L=128, V=64, P=0.1
// out[0 : B*L*V)          = compacted messages with EOS tail
// out[B*L*V : 2*B*L*V)    = rescaled probs
constexpr int Bn = 4096;
constexpr int Ln = 128;
constexpr int Vn = 64;
constexpr float KEEP = 0.9f;  // 1 - P

// native clang vector type — accepted by __builtin_nontemporal_{load,store}
typedef float f32x4 __attribute__((ext_vector_type(4)));

// ---- Kernel 1: stream-compact messages rows, EOS one-hot tail ----
__global__ __launch_bounds__(256) void deletion_msgs_kernel(
    const float* __restrict__ msgs,
    const int* __restrict__ mask,
    float* __restrict__ out)
{
    const int b    = blockIdx.x;
    const int tid  = threadIdx.x;
    const int lane = tid & 63;
    const int wave = tid >> 6;

    __shared__ int s_src[Ln];     // s_src[j] = source row of j-th kept symbol
    __shared__ int s_wavecnt[2];

    // compaction map from deletion mask (tid 0..127 = waves 0-1)
    bool kept = false;
    int rank = 0;
    if (tid < Ln) kept = (mask[(size_t)b * Ln + tid] == 0);
    if (wave < 2) {
        unsigned long long bal = __ballot(kept);
        rank = __popcll(bal & ((1ull << lane) - 1ull));
        if (lane == 0) s_wavecnt[wave] = (int)__popcll(bal);
    }
    __syncthreads();
    if (tid < Ln && kept) {
        const int off = (wave == 1) ? s_wavecnt[0] : 0;
        s_src[off + rank] = tid;
    }
    __syncthreads();
    const int nkept = s_wavecnt[0] + s_wavecnt[1];

    const size_t rowbase = (size_t)b * (Ln * Vn);  // floats
    const f32x4* __restrict__ src4 = (const f32x4*)(msgs + rowbase);
    f32x4* __restrict__ dst4       = (f32x4*)(out + rowbase);
    constexpr int TOT4 = Ln * Vn / 4;  // 2048 f32x4 per batch row
    #pragma unroll
    for (int it = 0; it < TOT4 / 256; ++it) {
        const int idx = it * 256 + tid;
        const int j = idx >> 4;    // output sequence position
        const int q = idx & 15;    // f32x4 within the 64-float row
        f32x4 v;
        if (j < nkept) {
            v = __builtin_nontemporal_load(&src4[(s_src[j] << 4) + q]);
        } else {
            v = (f32x4){(q == 0) ? 1.0f : 0.0f, 0.0f, 0.0f, 0.0f};  // EOS
        }
        __builtin_nontemporal_store(v, &dst4[idx]);
    }
}

// ---- Kernel 2: probs rescale — pure coalesced stream ----
__global__ __launch_bounds__(256) void deletion_probs_kernel(
    const float* __restrict__ probs,
    float* __restrict__ out)
{
    const int tid = threadIdx.x;
    const size_t base = (size_t)blockIdx.x * (2 * Ln * Vn / 4);  // 2 rows/block
    const f32x4* __restrict__ src4 = (const f32x4*)probs + base;
    f32x4* __restrict__ dst4 = (f32x4*)(out + (size_t)Bn * Ln * Vn) + base;
    constexpr int TOT4 = 2 * Ln * Vn / 4;  // 4096 f32x4 per block
    #pragma unroll
    for (int it = 0; it < TOT4 / 256; ++it) {
        const int idx = it * 256 + tid;
        const int q = idx & 15;
        const f32x4 p = __builtin_nontemporal_load(&src4[idx]);
        // tail sum (v >= 1) of this 64-float row, across its 16 lanes
        float s = p.x + p.y + p.z + p.w;
        if (q == 0) s -= p.x;           // exclude v=0
        s += __shfl_xor(s, 1);
        s += __shfl_xor(s, 2);
        s += __shfl_xor(s, 4);
        s += __shfl_xor(s, 8);
        f32x4 o = p * KEEP;
        if (q == 0) o.x = 1.0f - KEEP * s;  // EOS absorbs remainder
        __builtin_nontemporal_store(o, &dst4[idx]);
    }
}

extern "C" void kernel_launch(void* const* d_in, const int* in_sizes, int n_in,
                              void* d_out, int out_size, void* d_ws, size_t ws_size,
                              hipStream_t stream) {
    const float* msgs  = (const float*)d_in[0];
    const float* probs = (const float*)d_in[1];
    const int*   mask  = (const int*)d_in[2];
    float* out = (float*)d_out;

    deletion_msgs_kernel<<<Bn, 256, 0, stream>>>(msgs, mask, out);
    deletion_probs_kernel<<<Bn / 2, 256, 0, stream>>>(probs, out);
}